// Round 1
// baseline (200.029 us; speedup 1.0000x reference)
//
#include <hip/hip_runtime.h>
#include <hip/hip_bf16.h>

// Input: x [1, 512, 256, 256] f32, contiguous. Channel c = contiguous 65536 floats.
// Out: top-10 channel indices by mean (descending), int32.

#define C 512
#define HW 65536          // 256*256
#define K_TOP 10

__global__ __launch_bounds__(1024) void channel_sum_kernel(
    const float* __restrict__ x, float* __restrict__ sums) {
    const int c = blockIdx.x;
    const float4* xc = reinterpret_cast<const float4*>(x + (size_t)c * HW);
    const int tid = threadIdx.x;

    float s = 0.f;
#pragma unroll
    for (int i = 0; i < 16; ++i) {            // 16 * 1024 threads * 4 floats = 65536
        float4 v = xc[tid + i * 1024];
        s += (v.x + v.y) + (v.z + v.w);
    }

    // wave-64 shuffle reduction
#pragma unroll
    for (int off = 32; off > 0; off >>= 1) s += __shfl_down(s, off, 64);

    __shared__ float partial[16];
    const int wave = tid >> 6;
    const int lane = tid & 63;
    if (lane == 0) partial[wave] = s;
    __syncthreads();
    if (tid == 0) {
        float t = 0.f;
#pragma unroll
        for (int w = 0; w < 16; ++w) t += partial[w];
        sums[c] = t;                           // sum; ranking identical to mean
    }
}

__global__ __launch_bounds__(512) void topk_kernel(
    const float* __restrict__ sums, int* __restrict__ out) {
    __shared__ float vals[C];
    __shared__ float svals[C];
    __shared__ int   sidx[C];
    const int tid = threadIdx.x;

    vals[tid] = sums[tid];
    __syncthreads();

    for (int k = 0; k < K_TOP; ++k) {
        svals[tid] = vals[tid];
        sidx[tid]  = tid;
        __syncthreads();
#pragma unroll
        for (int s = 256; s > 0; s >>= 1) {
            if (tid < s) {
                float v2 = svals[tid + s];
                int   i2 = sidx[tid + s];
                // argmax; tie -> lower index (matches jax.lax.top_k)
                if (v2 > svals[tid] || (v2 == svals[tid] && i2 < sidx[tid])) {
                    svals[tid] = v2;
                    sidx[tid]  = i2;
                }
            }
            __syncthreads();
        }
        if (tid == 0) {
            out[k] = sidx[0];
            vals[sidx[0]] = -__builtin_inff();  // remove winner for next round
        }
        __syncthreads();
    }
}

extern "C" void kernel_launch(void* const* d_in, const int* in_sizes, int n_in,
                              void* d_out, int out_size, void* d_ws, size_t ws_size,
                              hipStream_t stream) {
    const float* x = (const float*)d_in[0];
    int* out = (int*)d_out;
    float* sums = (float*)d_ws;               // 512 floats of scratch

    channel_sum_kernel<<<C, 1024, 0, stream>>>(x, sums);
    topk_kernel<<<1, C, 0, stream>>>(sums, out);
}

// Round 2
// 193.534 us; speedup vs baseline: 1.0336x; 1.0336x over previous
//
#include <hip/hip_runtime.h>
#include <hip/hip_bf16.h>

// Input: x [1, 512, 256, 256] f32, contiguous. Channel c = contiguous 65536 floats.
// Out: top-10 channel indices by mean (descending), int32.

#define C 512
#define HW 65536            // 256*256
#define K_TOP 10
#define SEGS 8              // segments per channel
#define SEG_FLOATS (HW / SEGS)   // 8192 floats per segment

// Grid: C*SEGS = 4096 blocks x 256 threads. Each block sums one 8192-float
// contiguous segment (8 float4 per thread), fully coalesced.
__global__ __launch_bounds__(256) void partial_sum_kernel(
    const float* __restrict__ x, float* __restrict__ partials) {
    const int b = blockIdx.x;              // 0..4095
    const int c = b >> 3;
    const int seg = b & 7;
    const float4* p = reinterpret_cast<const float4*>(
        x + (size_t)c * HW + (size_t)seg * SEG_FLOATS);
    const int tid = threadIdx.x;

    float s = 0.f;
#pragma unroll
    for (int i = 0; i < 8; ++i) {          // 8 * 256 threads * 4 floats = 8192
        float4 v = p[tid + i * 256];
        s += (v.x + v.y) + (v.z + v.w);
    }

    // wave-64 shuffle reduction (no barrier)
#pragma unroll
    for (int off = 32; off > 0; off >>= 1) s += __shfl_down(s, off, 64);

    __shared__ float ps[4];
    if ((tid & 63) == 0) ps[tid >> 6] = s;
    __syncthreads();
    if (tid == 0) partials[b] = (ps[0] + ps[1]) + (ps[2] + ps[3]);
}

// One block, 512 threads: thread c sums its channel's 8 partials (deterministic
// order), then wave 0 does 10 barrier-free shuffle-butterfly argmax rounds.
__global__ __launch_bounds__(512) void finalize_topk_kernel(
    const float* __restrict__ partials, int* __restrict__ out) {
    __shared__ float vals[C];
    const int tid = threadIdx.x;

    float v = 0.f;
#pragma unroll
    for (int i = 0; i < SEGS; ++i) v += partials[tid * SEGS + i];
    vals[tid] = v;
    __syncthreads();

    if (tid < 64) {
        // each lane owns 8 channels: lane + 64*j
        float lv[8];
        int   li[8];
#pragma unroll
        for (int j = 0; j < 8; ++j) {
            li[j] = tid + 64 * j;
            lv[j] = vals[li[j]];
        }
        for (int k = 0; k < K_TOP; ++k) {
            // local argmax over this lane's 8 (tie -> lower index)
            float bv = lv[0]; int bi = li[0];
#pragma unroll
            for (int j = 1; j < 8; ++j)
                if (lv[j] > bv || (lv[j] == bv && li[j] < bi)) { bv = lv[j]; bi = li[j]; }
            // 64-lane butterfly argmax — all lanes converge to same winner
#pragma unroll
            for (int m = 1; m < 64; m <<= 1) {
                float ov = __shfl_xor(bv, m, 64);
                int   oi = __shfl_xor(bi, m, 64);
                if (ov > bv || (ov == bv && oi < bi)) { bv = ov; bi = oi; }
            }
            if (tid == 0) out[k] = bi;
            // remove winner from the owning lane
#pragma unroll
            for (int j = 0; j < 8; ++j)
                if (li[j] == bi) lv[j] = -__builtin_inff();
        }
    }
}

extern "C" void kernel_launch(void* const* d_in, const int* in_sizes, int n_in,
                              void* d_out, int out_size, void* d_ws, size_t ws_size,
                              hipStream_t stream) {
    const float* x = (const float*)d_in[0];
    int* out = (int*)d_out;
    float* partials = (float*)d_ws;        // C*SEGS = 4096 floats of scratch

    partial_sum_kernel<<<C * SEGS, 256, 0, stream>>>(x, partials);
    finalize_topk_kernel<<<1, C, 0, stream>>>(partials, out);
}